// Round 3
// baseline (3395.824 us; speedup 1.0000x reference)
//
#include <hip/hip_runtime.h>
#include <hip/hip_bf16.h>
#include <stdint.h>

// Model: B=4 S=4096 D=768 H=12 DH=64 BS=64 NB=64 NSEL=8 L=2 FF=3072
// Per-batch-element pipeline; ws ~59.8 MB. Runtime input-dtype probe (f32 vs bf16).

using bf16 = __hip_bfloat16;
typedef __bf16 bf16x8 __attribute__((ext_vector_type(8)));
typedef float f32x4 __attribute__((ext_vector_type(4)));

__device__ __forceinline__ float b2f(bf16 x) { return __bfloat162float(x); }
__device__ __forceinline__ bf16 f2b(float x) { return __float2bfloat16(x); }
// flag=1: raw input buffers hold bf16; flag=0: they hold f32.
__device__ __forceinline__ float ldf(const void* p, size_t i, int flag) {
  return flag ? __bfloat162float(((const bf16*)p)[i]) : ((const float*)p)[i];
}

__device__ __forceinline__ void gld_lds16(const bf16* g, bf16* l) {
  __builtin_amdgcn_global_load_lds((__attribute__((address_space(1))) void*)g,
                                   (__attribute__((address_space(3))) void*)l, 16, 0, 0);
}

__device__ __forceinline__ f32x4 mfma16(bf16x8 a, bf16x8 b, f32x4 c) {
  return __builtin_amdgcn_mfma_f32_16x16x32_bf16(a, b, c, 0, 0, 0);
}

// ---------------- dtype probe: ln_emb_g is all ones ----------------
__global__ void probe_kernel(const uint32_t* __restrict__ g, int* __restrict__ flag) {
  if (threadIdx.x == 0) flag[0] = (g[0] == 0x3F803F80u) ? 1 : 0;
}

// ---------------- weight transpose+convert: out[n*K+k] = bf16(in[off + k*N+n]) ----------------
__global__ __launch_bounds__(256) void transpose_k(const void* __restrict__ in, size_t in_off,
                                                   bf16* __restrict__ out, int K, int N,
                                                   const int* __restrict__ dflag) {
  __shared__ float tile[32][33];
  const int flag = dflag[0];
  const int bx = blockIdx.x * 32;  // n
  const int by = blockIdx.y * 32;  // k
  const int tx = threadIdx.x & 31, ty = threadIdx.x >> 5;  // 32x8
#pragma unroll
  for (int i = 0; i < 32; i += 8)
    tile[ty + i][tx] = ldf(in, in_off + (size_t)(by + ty + i) * N + bx + tx, flag);
  __syncthreads();
#pragma unroll
  for (int i = 0; i < 32; i += 8)
    out[(size_t)(bx + ty + i) * K + by + tx] = f2b(tile[tx][ty + i]);
}

// ---------------- embedding + LN ----------------
__global__ __launch_bounds__(256) void embed_ln_kernel(
    const int* __restrict__ ids, const void* __restrict__ emb, const void* __restrict__ pos,
    const void* __restrict__ g, const void* __restrict__ bb, bf16* __restrict__ h,
    const int* __restrict__ dflag) {
  __shared__ float red[8];
  const int flag = dflag[0];
  const int tok = blockIdx.x;
  const int tid = threadIdx.x;
  const int s = tok & 4095;
  const size_t id = (size_t)ids[tok];
  float v[3]; float sum = 0.f, sq = 0.f;
#pragma unroll
  for (int i = 0; i < 3; i++) {
    const int d = tid + i * 256;
    v[i] = ldf(emb, id * 768 + d, flag) + ldf(pos, (size_t)s * 768 + d, flag);
    sum += v[i]; sq += v[i] * v[i];
  }
#pragma unroll
  for (int off = 32; off >= 1; off >>= 1) { sum += __shfl_down(sum, off); sq += __shfl_down(sq, off); }
  if ((tid & 63) == 0) { red[(tid >> 6) * 2] = sum; red[(tid >> 6) * 2 + 1] = sq; }
  __syncthreads();
  sum = red[0] + red[2] + red[4] + red[6];
  sq  = red[1] + red[3] + red[5] + red[7];
  const float mean = sum * (1.0f / 768.0f);
  const float var = sq * (1.0f / 768.0f) - mean * mean;
  const float rs = rsqrtf(var + 1e-12f);
  bf16* hr = h + (size_t)tok * 768;
#pragma unroll
  for (int i = 0; i < 3; i++) {
    const int d = tid + i * 256;
    hr[d] = f2b((v[i] - mean) * rs * ldf(g, d, flag) + ldf(bb, d, flag));
  }
}

// ---------------- residual add + LN (in-place on h) ----------------
__global__ __launch_bounds__(256) void add_ln_kernel(
    bf16* __restrict__ h, const bf16* __restrict__ x,
    const void* __restrict__ g, const void* __restrict__ bb, size_t goff,
    const int* __restrict__ dflag) {
  __shared__ float red[8];
  const int flag = dflag[0];
  const int tok = blockIdx.x;
  const int tid = threadIdx.x;
  const size_t base = (size_t)tok * 768;
  float v[3]; float sum = 0.f, sq = 0.f;
#pragma unroll
  for (int i = 0; i < 3; i++) {
    const int d = tid + i * 256;
    v[i] = b2f(h[base + d]) + b2f(x[base + d]);
    sum += v[i]; sq += v[i] * v[i];
  }
#pragma unroll
  for (int off = 32; off >= 1; off >>= 1) { sum += __shfl_down(sum, off); sq += __shfl_down(sq, off); }
  if ((tid & 63) == 0) { red[(tid >> 6) * 2] = sum; red[(tid >> 6) * 2 + 1] = sq; }
  __syncthreads();
  sum = red[0] + red[2] + red[4] + red[6];
  sq  = red[1] + red[3] + red[5] + red[7];
  const float mean = sum * (1.0f / 768.0f);
  const float var = sq * (1.0f / 768.0f) - mean * mean;
  const float rs = rsqrtf(var + 1e-12f);
#pragma unroll
  for (int i = 0; i < 3; i++) {
    const int d = tid + i * 256;
    h[base + d] = f2b((v[i] - mean) * rs * ldf(g, goff + d, flag) + ldf(bb, goff + d, flag));
  }
}

// ---------------- GEMM: C[M,N] = A @ Bt^T + bias ----------------
// EPI 0: plain store. EPI 1: gelu(tanh). EPI 2: scatter into per-b blocked q/k/vT.
// ABLK: A is per-b blocked [hh][nb][pos][dh].
template <int EPI, bool ABLK>
__global__ __launch_bounds__(256) void gemm_bt(
    const bf16* __restrict__ A, const bf16* __restrict__ Bt,
    const void* __restrict__ bias, size_t bias_off, bf16* __restrict__ C,
    int N, int K,
    bf16* __restrict__ qout, bf16* __restrict__ kout, bf16* __restrict__ vout,
    const int* __restrict__ dflag) {
  __shared__ __align__(16) bf16 sA[128 * 32];
  __shared__ __align__(16) bf16 sB[128 * 32];
  const int m0 = blockIdx.x * 128;
  const int n0 = blockIdx.y * 128;
  const int tid = threadIdx.x;
  const int lane = tid & 63;
  const int wv = tid >> 6;
  const int wm = wv >> 1, wn = wv & 1;
  const int col = lane & 15, quad = lane >> 4;

  f32x4 acc[4][4] = {};

  const int sr = tid >> 2;          // staging row 0..63
  const int sc = (tid & 3) * 8;     // staging k-offset
  const bf16* gA = A + (size_t)(m0 + sr) * K + sc;
  const bf16* gB = Bt + (size_t)(n0 + sr) * K + sc;
  const size_t rstep = (size_t)64 * K;

  int cb0 = 0, cb1 = 0;
  if constexpr (ABLK) {
    const int t0 = m0 + sr, t1 = t0 + 64;       // token in [0,4096)
    cb0 = ((t0 >> 6) & 63) * 4096 + (t0 & 63) * 64;
    cb1 = ((t1 >> 6) & 63) * 4096 + (t1 & 63) * 64;
  }

  for (int k0 = 0; k0 < K; k0 += 32) {
    const bf16 *pA0, *pA1;
    if constexpr (ABLK) {
      const int c = k0 + sc;
      const int hh = c >> 6, dh = c & 63;
      pA0 = A + cb0 + hh * 262144 + dh;
      pA1 = A + cb1 + hh * 262144 + dh;
    } else {
      pA0 = gA; pA1 = gA + rstep; gA += 32;
    }
    gld_lds16(pA0, sA + tid * 8);
    gld_lds16(pA1, sA + 2048 + tid * 8);
    gld_lds16(gB, sB + tid * 8);
    gld_lds16(gB + rstep, sB + 2048 + tid * 8);
    gB += 32;
    __syncthreads();
    bf16x8 av[4], bv[4];
#pragma unroll
    for (int t = 0; t < 4; t++)
      av[t] = *(const bf16x8*)(sA + (wm * 64 + t * 16 + col) * 32 + quad * 8);
#pragma unroll
    for (int t = 0; t < 4; t++)
      bv[t] = *(const bf16x8*)(sB + (wn * 64 + t * 16 + col) * 32 + quad * 8);
#pragma unroll
    for (int mt = 0; mt < 4; mt++)
#pragma unroll
      for (int nt = 0; nt < 4; nt++)
        acc[mt][nt] = mfma16(av[mt], bv[nt], acc[mt][nt]);
    __syncthreads();
  }

  const int flag = dflag[0];
#pragma unroll
  for (int nt = 0; nt < 4; nt++) {
    const int n = n0 + wn * 64 + nt * 16 + col;
    const float bsv = ldf(bias, bias_off + n, flag);
#pragma unroll
    for (int mt = 0; mt < 4; mt++) {
#pragma unroll
      for (int r = 0; r < 4; r++) {
        const int m = m0 + wm * 64 + mt * 16 + quad * 4 + r;
        float val = acc[mt][nt][r] + bsv;
        if constexpr (EPI == 1) {
          val = 0.5f * val * (1.0f + tanhf(0.7978845608028654f * (val + 0.044715f * val * val * val)));
        }
        if constexpr (EPI == 2) {
          const int part = (n >= 1536) ? 2 : ((n >= 768) ? 1 : 0);
          const int within = n - part * 768;
          const int hh = within >> 6, dh = within & 63;
          const int nb = m >> 6, pos = m & 63;   // m = token in [0,4096)
          const size_t base = (size_t)(hh * 64 + nb) * 4096;
          if (part == 0)      qout[base + pos * 64 + dh] = f2b(val);
          else if (part == 1) kout[base + pos * 64 + dh] = f2b(val);
          else                vout[base + dh * 64 + pos] = f2b(val);
        } else {
          C[(size_t)m * N + n] = f2b(val);
        }
      }
    }
  }
}

// ---------------- block-sparse attention, per batch element ----------------
// grid: H*NB = 768 workgroups; writes O over its own Q block (block-local).
__global__ __launch_bounds__(256) void attn_kernel(
    const bf16* q, const bf16* __restrict__ kmat, const bf16* __restrict__ vT,
    const int* __restrict__ amask_b, const int* __restrict__ rand_idx, bf16* o) {
  __shared__ __align__(16) bf16 plds[4][16][32];
  const int idx = blockIdx.x;
  const int nb = idx & 63;
  const int hh = idx >> 6;
  const int tid = threadIdx.x;
  const int wv = tid >> 6, lane = tid & 63;
  const int col = lane & 15, quad = lane >> 4;

  int sel[8];
  sel[0] = 0; sel[1] = (nb + 63) & 63; sel[2] = nb; sel[3] = (nb + 1) & 63;
  sel[4] = 63;
  sel[5] = rand_idx[nb * 3 + 0];
  sel[6] = rand_idx[nb * 3 + 1];
  sel[7] = rand_idx[nb * 3 + 2];

  const size_t hbase = (size_t)hh * 64;
  const bf16* qb = q + (hbase + nb) * 4096;
  const int qrow = wv * 16 + col;
  const bf16x8 aq0 = *(const bf16x8*)(qb + qrow * 64 + quad * 8);
  const bf16x8 aq1 = *(const bf16x8*)(qb + qrow * 64 + 32 + quad * 8);

  float sreg[32][4];
#pragma unroll
  for (int sb = 0; sb < 8; sb++) {
    const bf16* kb = kmat + (hbase + sel[sb]) * 4096;
    const int* mrow = amask_b + sel[sb] * 64;
#pragma unroll
    for (int c = 0; c < 4; c++) {
      const int kr = c * 16 + col;
      const bf16x8 bk0 = *(const bf16x8*)(kb + kr * 64 + quad * 8);
      const bf16x8 bk1 = *(const bf16x8*)(kb + kr * 64 + 32 + quad * 8);
      f32x4 t = {};
      t = mfma16(aq0, bk0, t);
      t = mfma16(aq1, bk1, t);
      const float bias = (mrow[kr] > 0) ? 0.0f : -1e9f;
      const int ti = sb * 4 + c;
#pragma unroll
      for (int r = 0; r < 4; r++) sreg[ti][r] = t[r] * 0.125f + bias;
    }
  }

  float mx[4] = {-1e30f, -1e30f, -1e30f, -1e30f};
#pragma unroll
  for (int ti = 0; ti < 32; ti++)
#pragma unroll
    for (int r = 0; r < 4; r++) mx[r] = fmaxf(mx[r], sreg[ti][r]);
#pragma unroll
  for (int off = 8; off >= 1; off >>= 1)
#pragma unroll
    for (int r = 0; r < 4; r++) mx[r] = fmaxf(mx[r], __shfl_xor(mx[r], off));

  float sm[4] = {0.f, 0.f, 0.f, 0.f};
#pragma unroll
  for (int ti = 0; ti < 32; ti++)
#pragma unroll
    for (int r = 0; r < 4; r++) {
      const float p = __expf(sreg[ti][r] - mx[r]);
      sreg[ti][r] = p; sm[r] += p;
    }
#pragma unroll
  for (int off = 8; off >= 1; off >>= 1)
#pragma unroll
    for (int r = 0; r < 4; r++) sm[r] += __shfl_xor(sm[r], off);
  float inv[4];
#pragma unroll
  for (int r = 0; r < 4; r++) inv[r] = 1.0f / sm[r];

  f32x4 oacc[4] = {};
#pragma unroll
  for (int kc = 0; kc < 16; kc++) {
    __syncthreads();
#pragma unroll
    for (int j = 0; j < 2; j++)
#pragma unroll
      for (int r = 0; r < 4; r++)
        plds[wv][quad * 4 + r][j * 16 + col] = f2b(sreg[kc * 2 + j][r] * inv[r]);
    __syncthreads();
    const bf16x8 ap = *(const bf16x8*)(&plds[wv][col][quad * 8]);
    const int sb = kc >> 1;
    const int koff = (kc & 1) * 32 + quad * 8;
    const bf16* vb = vT + (hbase + sel[sb]) * 4096;
#pragma unroll
    for (int nt = 0; nt < 4; nt++) {
      const bf16x8 bvv = *(const bf16x8*)(vb + (nt * 16 + col) * 64 + koff);
      oacc[nt] = mfma16(ap, bvv, oacc[nt]);
    }
  }

  bf16* ob = o + (hbase + nb) * 4096;
#pragma unroll
  for (int nt = 0; nt < 4; nt++)
#pragma unroll
    for (int r = 0; r < 4; r++)
      ob[(wv * 16 + quad * 4 + r) * 64 + nt * 16 + col] = f2b(oacc[nt][r]);
}

// ---------------- pooler ----------------
__global__ __launch_bounds__(768) void pooler_kernel(
    const bf16* __restrict__ h, const void* __restrict__ Wp,
    const void* __restrict__ bp, float* __restrict__ pooled,
    const int* __restrict__ dflag) {
  __shared__ float hrow[768];
  const int flag = dflag[0];
  const int bb = blockIdx.x;
  const int j = threadIdx.x;
  hrow[j] = b2f(h[(size_t)bb * 4096 * 768 + j]);
  __syncthreads();
  float acc = 0.0f;
#pragma unroll 8
  for (int d = 0; d < 768; d++) acc += hrow[d] * ldf(Wp, (size_t)d * 768 + j, flag);
  pooled[bb * 768 + j] = tanhf(acc + ldf(bp, j, flag));
}

// ---------------- classifier + double-softmax loss ----------------
__global__ __launch_bounds__(256) void cls_kernel(
    const float* __restrict__ pooled, const void* __restrict__ Wc, const void* __restrict__ bc,
    const int* __restrict__ label, void* __restrict__ out, const int* __restrict__ dflag) {
  __shared__ float lsum[8];
  const int flag = dflag[0];
  const int tid = threadIdx.x;
  const int p = tid >> 5, i = tid & 31;
  const int bb = p >> 1, c = p & 1;
  float acc = 0.0f;
  for (int d = i; d < 768; d += 32) acc += pooled[bb * 768 + d] * ldf(Wc, (size_t)d * 2 + c, flag);
#pragma unroll
  for (int off = 16; off >= 1; off >>= 1) acc += __shfl_xor(acc, off);
  if (i == 0) lsum[p] = acc;
  __syncthreads();
  if (tid == 0) {
    float res[9];
    float loss = 0.0f;
    for (int b = 0; b < 4; b++) {
      const float l0 = lsum[b * 2 + 0] + ldf(bc, 0, flag);
      const float l1 = lsum[b * 2 + 1] + ldf(bc, 1, flag);
      const float m = fmaxf(l0, l1);
      const float e0 = expf(l0 - m), e1 = expf(l1 - m);
      const float s = e0 + e1;
      const float p0 = e0 / s, p1 = e1 / s;
      res[b * 2] = p0; res[b * 2 + 1] = p1;
      const float mm = fmaxf(p0, p1);
      const float lse = mm + logf(expf(p0 - mm) + expf(p1 - mm));
      const float chosen = (label[b] == 0) ? p0 : p1;
      loss -= (chosen - lse);
    }
    res[8] = loss * 0.25f;
    if (flag) { bf16* o = (bf16*)out; for (int j = 0; j < 9; j++) o[j] = f2b(res[j]); }
    else      { float* o = (float*)out; for (int j = 0; j < 9; j++) o[j] = res[j]; }
  }
}

extern "C" void kernel_launch(void* const* d_in, const int* in_sizes, int n_in,
                              void* d_out, int out_size, void* d_ws, size_t ws_size,
                              hipStream_t stream) {
  const int* input_ids      = (const int*)d_in[0];
  const int* attention_mask = (const int*)d_in[1];
  const int* label          = (const int*)d_in[2];
  const int* rand_idx       = (const int*)d_in[3];
  const void* emb      = d_in[4];
  const void* pos_emb  = d_in[5];
  const void* ln_emb_g = d_in[6];
  const void* ln_emb_b = d_in[7];
  const void* Wqkv = d_in[8];
  const void* bqkv = d_in[9];
  const void* Wo   = d_in[10];
  const void* bo   = d_in[11];
  const void* ln1_g = d_in[12];
  const void* ln1_b = d_in[13];
  const void* Wff1 = d_in[14];
  const void* bff1 = d_in[15];
  const void* Wff2 = d_in[16];
  const void* bff2 = d_in[17];
  const void* ln2_g = d_in[18];
  const void* ln2_b = d_in[19];
  const void* Wp = d_in[20];
  const void* bp = d_in[21];
  const void* Wc = d_in[22];
  const void* bc = d_in[23];

  // ws layout (bf16 elems), total ~29.9M elems = 59.8 MB
  bf16* ws = (bf16*)d_ws;
  size_t off = 0;
  int* dflag = (int*)(ws + off); off += 8;
  bf16* TwA  = ws + off; off += (size_t)3072 * 768;
  bf16* TwB  = ws + off; off += (size_t)3072 * 768;
  bf16* hbuf = ws + off; off += (size_t)16384 * 768;
  bf16* qo   = ws + off; off += (size_t)4096 * 768;   // per-b Q, then O; FF: a1 part 0
  bf16* kbf  = ws + off; off += (size_t)4096 * 768;   // per-b K; FF: a1 part 1
  bf16* vbf  = ws + off; off += (size_t)4096 * 768;   // per-b V^T
  bf16* xbf  = ws + off; off += (size_t)4096 * 768;   // per-b GEMM output
  bf16* a1s  = qo;                                    // [2048,3072] spans qo+kbf
  float* pooled = (float*)(ws + off); off += 6144;    // 3072 floats

  dim3 blk(256);

  probe_kernel<<<1, 64, 0, stream>>>((const uint32_t*)ln_emb_g, dflag);
  embed_ln_kernel<<<16384, blk, 0, stream>>>(input_ids, emb, pos_emb, ln_emb_g, ln_emb_b, hbuf, dflag);

  for (int l = 0; l < 2; l++) {
    transpose_k<<<dim3(72, 24), blk, 0, stream>>>(Wqkv, (size_t)l * 768 * 2304, TwA, 768, 2304, dflag);
    transpose_k<<<dim3(24, 24), blk, 0, stream>>>(Wo, (size_t)l * 768 * 768, TwB, 768, 768, dflag);
    for (int b = 0; b < 4; b++) {
      bf16* hb = hbuf + (size_t)b * 4096 * 768;
      gemm_bt<2, false><<<dim3(32, 18), blk, 0, stream>>>(hb, TwA, bqkv, (size_t)l * 2304,
                                                          nullptr, 2304, 768, qo, kbf, vbf, dflag);
      attn_kernel<<<768, blk, 0, stream>>>(qo, kbf, vbf, attention_mask + b * 4096, rand_idx, qo);
      gemm_bt<0, true><<<dim3(32, 6), blk, 0, stream>>>(qo, TwB, bo, (size_t)l * 768,
                                                        xbf, 768, 768, nullptr, nullptr, nullptr, dflag);
      add_ln_kernel<<<4096, blk, 0, stream>>>(hb, xbf, ln1_g, ln1_b, (size_t)l * 768, dflag);
    }
    transpose_k<<<dim3(96, 24), blk, 0, stream>>>(Wff1, (size_t)l * 768 * 3072, TwA, 768, 3072, dflag);
    transpose_k<<<dim3(24, 96), blk, 0, stream>>>(Wff2, (size_t)l * 3072 * 768, TwB, 3072, 768, dflag);
    for (int b = 0; b < 4; b++) {
      bf16* hb = hbuf + (size_t)b * 4096 * 768;
      for (int c = 0; c < 2; c++) {
        gemm_bt<1, false><<<dim3(16, 24), blk, 0, stream>>>(hb + (size_t)c * 2048 * 768, TwA, bff1,
                                                            (size_t)l * 3072, a1s, 3072, 768,
                                                            nullptr, nullptr, nullptr, dflag);
        gemm_bt<0, false><<<dim3(16, 6), blk, 0, stream>>>(a1s, TwB, bff2, (size_t)l * 768,
                                                           xbf + (size_t)c * 2048 * 768, 768, 3072,
                                                           nullptr, nullptr, nullptr, dflag);
      }
      add_ln_kernel<<<4096, blk, 0, stream>>>(hb, xbf, ln2_g, ln2_b, (size_t)l * 768, dflag);
    }
  }

  pooler_kernel<<<4, dim3(768), 0, stream>>>(hbuf, Wp, bp, pooled, dflag);
  cls_kernel<<<1, blk, 0, stream>>>(pooled, Wc, bc, label, d_out, dflag);

  (void)in_sizes; (void)n_in; (void)out_size; (void)ws_size;
}

// Round 4
// 1862.592 us; speedup vs baseline: 1.8232x; 1.8232x over previous
//
#include <hip/hip_runtime.h>
#include <hip/hip_bf16.h>
#include <stdint.h>

// Model: B=4 S=4096 D=768 H=12 DH=64 BS=64 NB=64 NSEL=8 L=2 FF=3072 M=16384
// Round 4: full-batch GEMMs (ws_size measured ~617 MB; round-3 per-batch split
// was grid-starved: FF2 ran at 96 workgroups / 256 CUs). Inputs are f32
// (round-3 probe) but keep the runtime dtype probe for robustness.

using bf16 = __hip_bfloat16;
typedef __bf16 bf16x8 __attribute__((ext_vector_type(8)));
typedef float f32x4 __attribute__((ext_vector_type(4)));

__device__ __forceinline__ float b2f(bf16 x) { return __bfloat162float(x); }
__device__ __forceinline__ bf16 f2b(float x) { return __float2bfloat16(x); }
// flag=1: raw input buffers hold bf16; flag=0: f32.
__device__ __forceinline__ float ldf(const void* p, size_t i, int flag) {
  return flag ? __bfloat162float(((const bf16*)p)[i]) : ((const float*)p)[i];
}

__device__ __forceinline__ void gld_lds16(const bf16* g, bf16* l) {
  __builtin_amdgcn_global_load_lds((__attribute__((address_space(1))) void*)g,
                                   (__attribute__((address_space(3))) void*)l, 16, 0, 0);
}

__device__ __forceinline__ f32x4 mfma16(bf16x8 a, bf16x8 b, f32x4 c) {
  return __builtin_amdgcn_mfma_f32_16x16x32_bf16(a, b, c, 0, 0, 0);
}

// ---------------- dtype probe: ln_emb_g is all ones ----------------
__global__ void probe_kernel(const uint32_t* __restrict__ g, int* __restrict__ flag) {
  if (threadIdx.x == 0) flag[0] = (g[0] == 0x3F803F80u) ? 1 : 0;
}

// ---------------- weight transpose+convert: out[n*K+k] = bf16(in[off + k*N+n]) ----------------
__global__ __launch_bounds__(256) void transpose_k(const void* __restrict__ in, size_t in_off,
                                                   bf16* __restrict__ out, int K, int N,
                                                   const int* __restrict__ dflag) {
  __shared__ float tile[32][33];
  const int flag = dflag[0];
  const int bx = blockIdx.x * 32;  // n
  const int by = blockIdx.y * 32;  // k
  const int tx = threadIdx.x & 31, ty = threadIdx.x >> 5;  // 32x8
#pragma unroll
  for (int i = 0; i < 32; i += 8)
    tile[ty + i][tx] = ldf(in, in_off + (size_t)(by + ty + i) * N + bx + tx, flag);
  __syncthreads();
#pragma unroll
  for (int i = 0; i < 32; i += 8)
    out[(size_t)(bx + ty + i) * K + by + tx] = f2b(tile[tx][ty + i]);
}

// ---------------- embedding + LN ----------------
__global__ __launch_bounds__(256) void embed_ln_kernel(
    const int* __restrict__ ids, const void* __restrict__ emb, const void* __restrict__ pos,
    const void* __restrict__ g, const void* __restrict__ bb, bf16* __restrict__ h,
    const int* __restrict__ dflag) {
  __shared__ float red[8];
  const int flag = dflag[0];
  const int tok = blockIdx.x;
  const int tid = threadIdx.x;
  const int s = tok & 4095;
  const size_t id = (size_t)ids[tok];
  float v[3]; float sum = 0.f, sq = 0.f;
#pragma unroll
  for (int i = 0; i < 3; i++) {
    const int d = tid + i * 256;
    v[i] = ldf(emb, id * 768 + d, flag) + ldf(pos, (size_t)s * 768 + d, flag);
    sum += v[i]; sq += v[i] * v[i];
  }
#pragma unroll
  for (int off = 32; off >= 1; off >>= 1) { sum += __shfl_down(sum, off); sq += __shfl_down(sq, off); }
  if ((tid & 63) == 0) { red[(tid >> 6) * 2] = sum; red[(tid >> 6) * 2 + 1] = sq; }
  __syncthreads();
  sum = red[0] + red[2] + red[4] + red[6];
  sq  = red[1] + red[3] + red[5] + red[7];
  const float mean = sum * (1.0f / 768.0f);
  const float var = sq * (1.0f / 768.0f) - mean * mean;
  const float rs = rsqrtf(var + 1e-12f);
  bf16* hr = h + (size_t)tok * 768;
#pragma unroll
  for (int i = 0; i < 3; i++) {
    const int d = tid + i * 256;
    hr[d] = f2b((v[i] - mean) * rs * ldf(g, d, flag) + ldf(bb, d, flag));
  }
}

// ---------------- residual add + LN (in-place on h) ----------------
__global__ __launch_bounds__(256) void add_ln_kernel(
    bf16* __restrict__ h, const bf16* __restrict__ x,
    const void* __restrict__ g, const void* __restrict__ bb, size_t goff,
    const int* __restrict__ dflag) {
  __shared__ float red[8];
  const int flag = dflag[0];
  const int tok = blockIdx.x;
  const int tid = threadIdx.x;
  const size_t base = (size_t)tok * 768;
  float v[3]; float sum = 0.f, sq = 0.f;
#pragma unroll
  for (int i = 0; i < 3; i++) {
    const int d = tid + i * 256;
    v[i] = b2f(h[base + d]) + b2f(x[base + d]);
    sum += v[i]; sq += v[i] * v[i];
  }
#pragma unroll
  for (int off = 32; off >= 1; off >>= 1) { sum += __shfl_down(sum, off); sq += __shfl_down(sq, off); }
  if ((tid & 63) == 0) { red[(tid >> 6) * 2] = sum; red[(tid >> 6) * 2 + 1] = sq; }
  __syncthreads();
  sum = red[0] + red[2] + red[4] + red[6];
  sq  = red[1] + red[3] + red[5] + red[7];
  const float mean = sum * (1.0f / 768.0f);
  const float var = sq * (1.0f / 768.0f) - mean * mean;
  const float rs = rsqrtf(var + 1e-12f);
#pragma unroll
  for (int i = 0; i < 3; i++) {
    const int d = tid + i * 256;
    h[base + d] = f2b((v[i] - mean) * rs * ldf(g, goff + d, flag) + ldf(bb, goff + d, flag));
  }
}

// ---------------- GEMM: C[M,N] = A @ Bt^T + bias ----------------
// EPI 0: plain store. EPI 1: gelu(tanh). EPI 2: scatter into blocked q/k/vT (full batch).
// ABLK: A is blocked [bb][hh][nb][pos][dh] (attention output, full batch).
template <int EPI, bool ABLK>
__global__ __launch_bounds__(256) void gemm_bt(
    const bf16* __restrict__ A, const bf16* __restrict__ Bt,
    const void* __restrict__ bias, size_t bias_off, bf16* __restrict__ C,
    int N, int K,
    bf16* __restrict__ qout, bf16* __restrict__ kout, bf16* __restrict__ vout,
    const int* __restrict__ dflag) {
  __shared__ __align__(16) bf16 sA[128 * 32];
  __shared__ __align__(16) bf16 sB[128 * 32];
  const int m0 = blockIdx.x * 128;
  const int n0 = blockIdx.y * 128;
  const int tid = threadIdx.x;
  const int lane = tid & 63;
  const int wv = tid >> 6;
  const int wm = wv >> 1, wn = wv & 1;
  const int col = lane & 15, quad = lane >> 4;

  f32x4 acc[4][4] = {};

  const int sr = tid >> 2;          // staging row 0..63
  const int sc = (tid & 3) * 8;     // staging k-offset
  const bf16* gA = A + (size_t)(m0 + sr) * K + sc;
  const bf16* gB = Bt + (size_t)(n0 + sr) * K + sc;
  const size_t rstep = (size_t)64 * K;

  size_t cb0 = 0, cb1 = 0;
  if constexpr (ABLK) {
    const int t0 = m0 + sr, t1 = t0 + 64;   // token in [0,16384)
    cb0 = (size_t)(t0 >> 12) * 3145728 + ((t0 >> 6) & 63) * 4096 + (t0 & 63) * 64;
    cb1 = (size_t)(t1 >> 12) * 3145728 + ((t1 >> 6) & 63) * 4096 + (t1 & 63) * 64;
  }

  for (int k0 = 0; k0 < K; k0 += 32) {
    const bf16 *pA0, *pA1;
    if constexpr (ABLK) {
      const int c = k0 + sc;
      const int hh = c >> 6, dh = c & 63;
      pA0 = A + cb0 + hh * 262144 + dh;
      pA1 = A + cb1 + hh * 262144 + dh;
    } else {
      pA0 = gA; pA1 = gA + rstep; gA += 32;
    }
    gld_lds16(pA0, sA + tid * 8);
    gld_lds16(pA1, sA + 2048 + tid * 8);
    gld_lds16(gB, sB + tid * 8);
    gld_lds16(gB + rstep, sB + 2048 + tid * 8);
    gB += 32;
    __syncthreads();
    bf16x8 av[4], bv[4];
#pragma unroll
    for (int t = 0; t < 4; t++)
      av[t] = *(const bf16x8*)(sA + (wm * 64 + t * 16 + col) * 32 + quad * 8);
#pragma unroll
    for (int t = 0; t < 4; t++)
      bv[t] = *(const bf16x8*)(sB + (wn * 64 + t * 16 + col) * 32 + quad * 8);
#pragma unroll
    for (int mt = 0; mt < 4; mt++)
#pragma unroll
      for (int nt = 0; nt < 4; nt++)
        acc[mt][nt] = mfma16(av[mt], bv[nt], acc[mt][nt]);
    __syncthreads();
  }

  const int flag = dflag[0];
#pragma unroll
  for (int nt = 0; nt < 4; nt++) {
    const int n = n0 + wn * 64 + nt * 16 + col;
    const float bsv = ldf(bias, bias_off + n, flag);
#pragma unroll
    for (int mt = 0; mt < 4; mt++) {
#pragma unroll
      for (int r = 0; r < 4; r++) {
        const int m = m0 + wm * 64 + mt * 16 + quad * 4 + r;
        float val = acc[mt][nt][r] + bsv;
        if constexpr (EPI == 1) {
          val = 0.5f * val * (1.0f + tanhf(0.7978845608028654f * (val + 0.044715f * val * val * val)));
        }
        if constexpr (EPI == 2) {
          const int part = (n >= 1536) ? 2 : ((n >= 768) ? 1 : 0);
          const int within = n - part * 768;
          const int hh = within >> 6, dh = within & 63;
          const int bb = m >> 12;
          const int nb = (m >> 6) & 63, pos = m & 63;
          const size_t base = (size_t)((bb * 12 + hh) * 64 + nb) * 4096;
          if (part == 0)      qout[base + pos * 64 + dh] = f2b(val);
          else if (part == 1) kout[base + pos * 64 + dh] = f2b(val);
          else                vout[base + dh * 64 + pos] = f2b(val);
        } else {
          C[(size_t)m * N + n] = f2b(val);
        }
      }
    }
  }
}

// ---------------- block-sparse attention, full batch ----------------
// grid: B*H*NB = 3072 workgroups; writes O over its own Q block (block-local).
__global__ __launch_bounds__(256) void attn_kernel(
    const bf16* q, const bf16* __restrict__ kmat, const bf16* __restrict__ vT,
    const int* __restrict__ amask, const int* __restrict__ rand_idx, bf16* o) {
  __shared__ __align__(16) bf16 plds[4][16][32];
  const int idx = blockIdx.x;
  const int nb = idx & 63;
  const int bh = idx >> 6;           // bb*12+hh
  const int bb = bh / 12;
  const int tid = threadIdx.x;
  const int wv = tid >> 6, lane = tid & 63;
  const int col = lane & 15, quad = lane >> 4;

  int sel[8];
  sel[0] = 0; sel[1] = (nb + 63) & 63; sel[2] = nb; sel[3] = (nb + 1) & 63;
  sel[4] = 63;
  sel[5] = rand_idx[nb * 3 + 0];
  sel[6] = rand_idx[nb * 3 + 1];
  sel[7] = rand_idx[nb * 3 + 2];

  const size_t bhbase = (size_t)bh * 64;
  const bf16* qb = q + (bhbase + nb) * 4096;
  const int qrow = wv * 16 + col;
  const bf16x8 aq0 = *(const bf16x8*)(qb + qrow * 64 + quad * 8);
  const bf16x8 aq1 = *(const bf16x8*)(qb + qrow * 64 + 32 + quad * 8);

  float sreg[32][4];
#pragma unroll
  for (int sb = 0; sb < 8; sb++) {
    const bf16* kb = kmat + (bhbase + sel[sb]) * 4096;
    const int* mrow = amask + bb * 4096 + sel[sb] * 64;
#pragma unroll
    for (int c = 0; c < 4; c++) {
      const int kr = c * 16 + col;
      const bf16x8 bk0 = *(const bf16x8*)(kb + kr * 64 + quad * 8);
      const bf16x8 bk1 = *(const bf16x8*)(kb + kr * 64 + 32 + quad * 8);
      f32x4 t = {};
      t = mfma16(aq0, bk0, t);
      t = mfma16(aq1, bk1, t);
      const float bias = (mrow[kr] > 0) ? 0.0f : -1e9f;
      const int ti = sb * 4 + c;
#pragma unroll
      for (int r = 0; r < 4; r++) sreg[ti][r] = t[r] * 0.125f + bias;
    }
  }

  float mx[4] = {-1e30f, -1e30f, -1e30f, -1e30f};
#pragma unroll
  for (int ti = 0; ti < 32; ti++)
#pragma unroll
    for (int r = 0; r < 4; r++) mx[r] = fmaxf(mx[r], sreg[ti][r]);
#pragma unroll
  for (int off = 8; off >= 1; off >>= 1)
#pragma unroll
    for (int r = 0; r < 4; r++) mx[r] = fmaxf(mx[r], __shfl_xor(mx[r], off));

  float sm[4] = {0.f, 0.f, 0.f, 0.f};
#pragma unroll
  for (int ti = 0; ti < 32; ti++)
#pragma unroll
    for (int r = 0; r < 4; r++) {
      const float p = __expf(sreg[ti][r] - mx[r]);
      sreg[ti][r] = p; sm[r] += p;
    }
#pragma unroll
  for (int off = 8; off >= 1; off >>= 1)
#pragma unroll
    for (int r = 0; r < 4; r++) sm[r] += __shfl_xor(sm[r], off);
  float inv[4];
#pragma unroll
  for (int r = 0; r < 4; r++) inv[r] = 1.0f / sm[r];

  f32x4 oacc[4] = {};
#pragma unroll
  for (int kc = 0; kc < 16; kc++) {
    __syncthreads();
#pragma unroll
    for (int j = 0; j < 2; j++)
#pragma unroll
      for (int r = 0; r < 4; r++)
        plds[wv][quad * 4 + r][j * 16 + col] = f2b(sreg[kc * 2 + j][r] * inv[r]);
    __syncthreads();
    const bf16x8 ap = *(const bf16x8*)(&plds[wv][col][quad * 8]);
    const int sb = kc >> 1;
    const int koff = (kc & 1) * 32 + quad * 8;
    const bf16* vb = vT + (bhbase + sel[sb]) * 4096;
#pragma unroll
    for (int nt = 0; nt < 4; nt++) {
      const bf16x8 bvv = *(const bf16x8*)(vb + (nt * 16 + col) * 64 + koff);
      oacc[nt] = mfma16(ap, bvv, oacc[nt]);
    }
  }

  bf16* ob = o + (bhbase + nb) * 4096;
#pragma unroll
  for (int nt = 0; nt < 4; nt++)
#pragma unroll
    for (int r = 0; r < 4; r++)
      ob[(wv * 16 + quad * 4 + r) * 64 + nt * 16 + col] = f2b(oacc[nt][r]);
}

// ---------------- pooler ----------------
__global__ __launch_bounds__(768) void pooler_kernel(
    const bf16* __restrict__ h, const void* __restrict__ Wp,
    const void* __restrict__ bp, float* __restrict__ pooled,
    const int* __restrict__ dflag) {
  __shared__ float hrow[768];
  const int flag = dflag[0];
  const int bb = blockIdx.x;
  const int j = threadIdx.x;
  hrow[j] = b2f(h[(size_t)bb * 4096 * 768 + j]);
  __syncthreads();
  float acc = 0.0f;
#pragma unroll 8
  for (int d = 0; d < 768; d++) acc += hrow[d] * ldf(Wp, (size_t)d * 768 + j, flag);
  pooled[bb * 768 + j] = tanhf(acc + ldf(bp, j, flag));
}

// ---------------- classifier + double-softmax loss ----------------
__global__ __launch_bounds__(256) void cls_kernel(
    const float* __restrict__ pooled, const void* __restrict__ Wc, const void* __restrict__ bc,
    const int* __restrict__ label, void* __restrict__ out, const int* __restrict__ dflag) {
  __shared__ float lsum[8];
  const int flag = dflag[0];
  const int tid = threadIdx.x;
  const int p = tid >> 5, i = tid & 31;
  const int bb = p >> 1, c = p & 1;
  float acc = 0.0f;
  for (int d = i; d < 768; d += 32) acc += pooled[bb * 768 + d] * ldf(Wc, (size_t)d * 2 + c, flag);
#pragma unroll
  for (int off = 16; off >= 1; off >>= 1) acc += __shfl_xor(acc, off);
  if (i == 0) lsum[p] = acc;
  __syncthreads();
  if (tid == 0) {
    float res[9];
    float loss = 0.0f;
    for (int b = 0; b < 4; b++) {
      const float l0 = lsum[b * 2 + 0] + ldf(bc, 0, flag);
      const float l1 = lsum[b * 2 + 1] + ldf(bc, 1, flag);
      const float m = fmaxf(l0, l1);
      const float e0 = expf(l0 - m), e1 = expf(l1 - m);
      const float s = e0 + e1;
      const float p0 = e0 / s, p1 = e1 / s;
      res[b * 2] = p0; res[b * 2 + 1] = p1;
      const float mm = fmaxf(p0, p1);
      const float lse = mm + logf(expf(p0 - mm) + expf(p1 - mm));
      const float chosen = (label[b] == 0) ? p0 : p1;
      loss -= (chosen - lse);
    }
    res[8] = loss * 0.25f;
    if (flag) { bf16* o = (bf16*)out; for (int j = 0; j < 9; j++) o[j] = f2b(res[j]); }
    else      { float* o = (float*)out; for (int j = 0; j < 9; j++) o[j] = res[j]; }
  }
}

extern "C" void kernel_launch(void* const* d_in, const int* in_sizes, int n_in,
                              void* d_out, int out_size, void* d_ws, size_t ws_size,
                              hipStream_t stream) {
  const int* input_ids      = (const int*)d_in[0];
  const int* attention_mask = (const int*)d_in[1];
  const int* label          = (const int*)d_in[2];
  const int* rand_idx       = (const int*)d_in[3];
  const void* emb      = d_in[4];
  const void* pos_emb  = d_in[5];
  const void* ln_emb_g = d_in[6];
  const void* ln_emb_b = d_in[7];
  const void* Wqkv = d_in[8];
  const void* bqkv = d_in[9];
  const void* Wo   = d_in[10];
  const void* bo   = d_in[11];
  const void* ln1_g = d_in[12];
  const void* ln1_b = d_in[13];
  const void* Wff1 = d_in[14];
  const void* bff1 = d_in[15];
  const void* Wff2 = d_in[16];
  const void* bff2 = d_in[17];
  const void* ln2_g = d_in[18];
  const void* ln2_b = d_in[19];
  const void* Wp = d_in[20];
  const void* bp = d_in[21];
  const void* Wc = d_in[22];
  const void* bc = d_in[23];

  // ws layout (bf16 elems): ~255 MB total, ws_size ~617 MB (measured round 3).
  bf16* ws = (bf16*)d_ws;
  size_t off = 0;
  int* dflag = (int*)(ws + off); off += 8;
  bf16* WqkvT = ws + off; off += (size_t)2 * 2304 * 768;
  bf16* WoT   = ws + off; off += (size_t)2 * 768 * 768;
  bf16* Wff1T = ws + off; off += (size_t)2 * 3072 * 768;
  bf16* Wff2T = ws + off; off += (size_t)2 * 768 * 3072;
  bf16* hbuf  = ws + off; off += (size_t)16384 * 768;
  bf16* qo    = ws + off; off += (size_t)16384 * 768;   // Q then O (blocked)
  bf16* kbf   = ws + off; off += (size_t)16384 * 768;   // K (blocked)
  bf16* vbf   = ws + off; off += (size_t)16384 * 768;   // V^T (blocked)
  bf16* xbf   = ws + off; off += (size_t)16384 * 768;   // GEMM out (row-major)
  bf16* a1buf = ws + off; off += (size_t)16384 * 3072;  // gelu acts
  float* pooled = (float*)(ws + off); off += 6144;

  dim3 blk(256);

  probe_kernel<<<1, 64, 0, stream>>>((const uint32_t*)ln_emb_g, dflag);

  // transpose all weights once
  for (int l = 0; l < 2; l++) {
    transpose_k<<<dim3(72, 24), blk, 0, stream>>>(Wqkv, (size_t)l * 768 * 2304, WqkvT + (size_t)l * 2304 * 768, 768, 2304, dflag);
    transpose_k<<<dim3(24, 24), blk, 0, stream>>>(Wo, (size_t)l * 768 * 768, WoT + (size_t)l * 768 * 768, 768, 768, dflag);
    transpose_k<<<dim3(96, 24), blk, 0, stream>>>(Wff1, (size_t)l * 768 * 3072, Wff1T + (size_t)l * 3072 * 768, 768, 3072, dflag);
    transpose_k<<<dim3(24, 96), blk, 0, stream>>>(Wff2, (size_t)l * 3072 * 768, Wff2T + (size_t)l * 768 * 3072, 3072, 768, dflag);
  }

  embed_ln_kernel<<<16384, blk, 0, stream>>>(input_ids, emb, pos_emb, ln_emb_g, ln_emb_b, hbuf, dflag);

  for (int l = 0; l < 2; l++) {
    gemm_bt<2, false><<<dim3(128, 18), blk, 0, stream>>>(hbuf, WqkvT + (size_t)l * 2304 * 768, bqkv, (size_t)l * 2304,
                                                         nullptr, 2304, 768, qo, kbf, vbf, dflag);
    attn_kernel<<<3072, blk, 0, stream>>>(qo, kbf, vbf, attention_mask, rand_idx, qo);
    gemm_bt<0, true><<<dim3(128, 6), blk, 0, stream>>>(qo, WoT + (size_t)l * 768 * 768, bo, (size_t)l * 768,
                                                       xbf, 768, 768, nullptr, nullptr, nullptr, dflag);
    add_ln_kernel<<<16384, blk, 0, stream>>>(hbuf, xbf, ln1_g, ln1_b, (size_t)l * 768, dflag);
    gemm_bt<1, false><<<dim3(128, 24), blk, 0, stream>>>(hbuf, Wff1T + (size_t)l * 3072 * 768, bff1, (size_t)l * 3072,
                                                         a1buf, 3072, 768, nullptr, nullptr, nullptr, dflag);
    gemm_bt<0, false><<<dim3(128, 6), blk, 0, stream>>>(a1buf, Wff2T + (size_t)l * 768 * 3072, bff2, (size_t)l * 768,
                                                        xbf, 768, 3072, nullptr, nullptr, nullptr, dflag);
    add_ln_kernel<<<16384, blk, 0, stream>>>(hbuf, xbf, ln2_g, ln2_b, (size_t)l * 768, dflag);
  }

  pooler_kernel<<<4, dim3(768), 0, stream>>>(hbuf, Wp, bp, pooled, dflag);
  cls_kernel<<<1, blk, 0, stream>>>(pooled, Wc, bc, label, d_out, dflag);

  (void)in_sizes; (void)n_in; (void)out_size; (void)ws_size;
}

// Round 5
// 1790.013 us; speedup vs baseline: 1.8971x; 1.0405x over previous
//
#include <hip/hip_runtime.h>
#include <hip/hip_bf16.h>
#include <stdint.h>

// Model: B=4 S=4096 D=768 H=12 DH=64 BS=64 NB=64 NSEL=8 L=2 FF=3072 M=16384
// Round 5: GEMM fixes — (1) LDS bank-conflict swizzle (K-chunk rotated by
// (row>>2)&3; global source permuted per-lane since global_load_lds LDS dest
// is lane-fixed), (2) LDS-staged vectorized epilogue stores (incl. V^T
// transpose in LDS), (3) fast gelu via __expf sigmoid form.

using bf16 = __hip_bfloat16;
typedef __bf16 bf16x8 __attribute__((ext_vector_type(8)));
typedef __bf16 bf16x4 __attribute__((ext_vector_type(4)));
typedef float f32x4 __attribute__((ext_vector_type(4)));

__device__ __forceinline__ float b2f(bf16 x) { return __bfloat162float(x); }
__device__ __forceinline__ bf16 f2b(float x) { return __float2bfloat16(x); }
// flag=1: raw input buffers hold bf16; flag=0: f32.
__device__ __forceinline__ float ldf(const void* p, size_t i, int flag) {
  return flag ? __bfloat162float(((const bf16*)p)[i]) : ((const float*)p)[i];
}

__device__ __forceinline__ void gld_lds16(const bf16* g, bf16* l) {
  __builtin_amdgcn_global_load_lds((__attribute__((address_space(1))) void*)g,
                                   (__attribute__((address_space(3))) void*)l, 16, 0, 0);
}

__device__ __forceinline__ f32x4 mfma16(bf16x8 a, bf16x8 b, f32x4 c) {
  return __builtin_amdgcn_mfma_f32_16x16x32_bf16(a, b, c, 0, 0, 0);
}

// gelu(tanh approx) == x * sigmoid(2*0.79788456*(x + 0.044715 x^3))
__device__ __forceinline__ float gelu_f(float x) {
  const float z = 1.5957691216057308f * (x + 0.044715f * x * x * x);
  return x / (1.0f + __expf(-z));
}

// ---------------- dtype probe: ln_emb_g is all ones ----------------
__global__ void probe_kernel(const uint32_t* __restrict__ g, int* __restrict__ flag) {
  if (threadIdx.x == 0) flag[0] = (g[0] == 0x3F803F80u) ? 1 : 0;
}

// ---------------- weight transpose+convert ----------------
__global__ __launch_bounds__(256) void transpose_k(const void* __restrict__ in, size_t in_off,
                                                   bf16* __restrict__ out, int K, int N,
                                                   const int* __restrict__ dflag) {
  __shared__ float tile[32][33];
  const int flag = dflag[0];
  const int bx = blockIdx.x * 32;  // n
  const int by = blockIdx.y * 32;  // k
  const int tx = threadIdx.x & 31, ty = threadIdx.x >> 5;  // 32x8
#pragma unroll
  for (int i = 0; i < 32; i += 8)
    tile[ty + i][tx] = ldf(in, in_off + (size_t)(by + ty + i) * N + bx + tx, flag);
  __syncthreads();
#pragma unroll
  for (int i = 0; i < 32; i += 8)
    out[(size_t)(bx + ty + i) * K + by + tx] = f2b(tile[tx][ty + i]);
}

// ---------------- embedding + LN ----------------
__global__ __launch_bounds__(256) void embed_ln_kernel(
    const int* __restrict__ ids, const void* __restrict__ emb, const void* __restrict__ pos,
    const void* __restrict__ g, const void* __restrict__ bb, bf16* __restrict__ h,
    const int* __restrict__ dflag) {
  __shared__ float red[8];
  const int flag = dflag[0];
  const int tok = blockIdx.x;
  const int tid = threadIdx.x;
  const int s = tok & 4095;
  const size_t id = (size_t)ids[tok];
  float v[3]; float sum = 0.f, sq = 0.f;
#pragma unroll
  for (int i = 0; i < 3; i++) {
    const int d = tid + i * 256;
    v[i] = ldf(emb, id * 768 + d, flag) + ldf(pos, (size_t)s * 768 + d, flag);
    sum += v[i]; sq += v[i] * v[i];
  }
#pragma unroll
  for (int off = 32; off >= 1; off >>= 1) { sum += __shfl_down(sum, off); sq += __shfl_down(sq, off); }
  if ((tid & 63) == 0) { red[(tid >> 6) * 2] = sum; red[(tid >> 6) * 2 + 1] = sq; }
  __syncthreads();
  sum = red[0] + red[2] + red[4] + red[6];
  sq  = red[1] + red[3] + red[5] + red[7];
  const float mean = sum * (1.0f / 768.0f);
  const float var = sq * (1.0f / 768.0f) - mean * mean;
  const float rs = rsqrtf(var + 1e-12f);
  bf16* hr = h + (size_t)tok * 768;
#pragma unroll
  for (int i = 0; i < 3; i++) {
    const int d = tid + i * 256;
    hr[d] = f2b((v[i] - mean) * rs * ldf(g, d, flag) + ldf(bb, d, flag));
  }
}

// ---------------- residual add + LN (in-place on h) ----------------
__global__ __launch_bounds__(256) void add_ln_kernel(
    bf16* __restrict__ h, const bf16* __restrict__ x,
    const void* __restrict__ g, const void* __restrict__ bb, size_t goff,
    const int* __restrict__ dflag) {
  __shared__ float red[8];
  const int flag = dflag[0];
  const int tok = blockIdx.x;
  const int tid = threadIdx.x;
  const size_t base = (size_t)tok * 768;
  float v[3]; float sum = 0.f, sq = 0.f;
#pragma unroll
  for (int i = 0; i < 3; i++) {
    const int d = tid + i * 256;
    v[i] = b2f(h[base + d]) + b2f(x[base + d]);
    sum += v[i]; sq += v[i] * v[i];
  }
#pragma unroll
  for (int off = 32; off >= 1; off >>= 1) { sum += __shfl_down(sum, off); sq += __shfl_down(sq, off); }
  if ((tid & 63) == 0) { red[(tid >> 6) * 2] = sum; red[(tid >> 6) * 2 + 1] = sq; }
  __syncthreads();
  sum = red[0] + red[2] + red[4] + red[6];
  sq  = red[1] + red[3] + red[5] + red[7];
  const float mean = sum * (1.0f / 768.0f);
  const float var = sq * (1.0f / 768.0f) - mean * mean;
  const float rs = rsqrtf(var + 1e-12f);
#pragma unroll
  for (int i = 0; i < 3; i++) {
    const int d = tid + i * 256;
    h[base + d] = f2b((v[i] - mean) * rs * ldf(g, goff + d, flag) + ldf(bb, goff + d, flag));
  }
}

// ---------------- GEMM: C[M,N] = A @ Bt^T + bias ----------------
// EPI 0: plain store. EPI 1: gelu. EPI 2: scatter into blocked q/k/vT (full batch).
// ABLK: A is blocked [bb][hh][nb][pos][dh].
template <int EPI, bool ABLK>
__global__ __launch_bounds__(256) void gemm_bt(
    const bf16* __restrict__ A, const bf16* __restrict__ Bt,
    const void* __restrict__ bias, size_t bias_off, bf16* __restrict__ C,
    int N, int K,
    bf16* __restrict__ qout, bf16* __restrict__ kout, bf16* __restrict__ vout,
    const int* __restrict__ dflag) {
  __shared__ __align__(16) bf16 smem[9216];   // main loop: sA(4096)+sB(4096); epilogue scratch
  bf16* sA = smem;
  bf16* sB = smem + 4096;
  const int m0 = blockIdx.x * 128;
  const int n0 = blockIdx.y * 128;
  const int tid = threadIdx.x;
  const int lane = tid & 63;
  const int wv = tid >> 6;
  const int wm = wv >> 1, wn = wv & 1;
  const int col = lane & 15, quad = lane >> 4;

  f32x4 acc[4][4] = {};

  // Staging: lane holds LDS (row=tid>>2, slot=tid&3); slot s stores global
  // chunk (s - (row>>2)) & 3  (bank-conflict swizzle).
  const int sr = tid >> 2;                                   // row 0..63
  const int kc = ((tid & 3) - ((tid >> 4) & 3)) & 3;         // global chunk for this lane
  const int sc = kc * 8;
  const bf16* gA = A + (size_t)(m0 + sr) * K + sc;
  const bf16* gB = Bt + (size_t)(n0 + sr) * K + sc;
  const size_t rstep = (size_t)64 * K;

  size_t cb0 = 0, cb1 = 0;
  if constexpr (ABLK) {
    const int t0 = m0 + sr, t1 = t0 + 64;   // token in [0,16384)
    cb0 = (size_t)(t0 >> 12) * 3145728 + ((t0 >> 6) & 63) * 4096 + (t0 & 63) * 64;
    cb1 = (size_t)(t1 >> 12) * 3145728 + ((t1 >> 6) & 63) * 4096 + (t1 & 63) * 64;
  }

  // Fragment read slot: chunk wanted = quad, row swizzle = (col>>2)&3
  const int sl = (quad + (col >> 2)) & 3;

  for (int k0 = 0; k0 < K; k0 += 32) {
    const bf16 *pA0, *pA1;
    if constexpr (ABLK) {
      const int c = k0 + sc;
      const int hh = c >> 6, dh = c & 63;
      pA0 = A + cb0 + hh * 262144 + dh;
      pA1 = A + cb1 + hh * 262144 + dh;
    } else {
      pA0 = gA; pA1 = gA + rstep; gA += 32;
    }
    gld_lds16(pA0, sA + tid * 8);
    gld_lds16(pA1, sA + 2048 + tid * 8);
    gld_lds16(gB, sB + tid * 8);
    gld_lds16(gB + rstep, sB + 2048 + tid * 8);
    gB += 32;
    __syncthreads();
    bf16x8 av[4], bv[4];
#pragma unroll
    for (int t = 0; t < 4; t++)
      av[t] = *(const bf16x8*)(sA + (wm * 64 + t * 16 + col) * 32 + sl * 8);
#pragma unroll
    for (int t = 0; t < 4; t++)
      bv[t] = *(const bf16x8*)(sB + (wn * 64 + t * 16 + col) * 32 + sl * 8);
#pragma unroll
    for (int mt = 0; mt < 4; mt++)
#pragma unroll
      for (int nt = 0; nt < 4; nt++)
        acc[mt][nt] = mfma16(av[mt], bv[nt], acc[mt][nt]);
    __syncthreads();
  }

  const int flag = dflag[0];
  float bsv[4];
#pragma unroll
  for (int nt = 0; nt < 4; nt++)
    bsv[nt] = ldf(bias, bias_off + n0 + wn * 64 + nt * 16 + col, flag);

  if constexpr (EPI != 2) {
    // LDS-staged coalesced store, half-tile (64 x 128) at a time. Pitch 136
    // (16B-aligned rows, spreads banks).
    for (int half = 0; half < 2; half++) {
      __syncthreads();
      if (wm == half) {
#pragma unroll
        for (int nt = 0; nt < 4; nt++)
#pragma unroll
          for (int mt = 0; mt < 4; mt++)
#pragma unroll
            for (int r = 0; r < 4; r++) {
              float val = acc[mt][nt][r] + bsv[nt];
              if constexpr (EPI == 1) val = gelu_f(val);
              smem[(mt * 16 + quad * 4 + r) * 136 + wn * 64 + nt * 16 + col] = f2b(val);
            }
      }
      __syncthreads();
#pragma unroll
      for (int rr = 0; rr < 4; rr++) {
        const int row = rr * 16 + (tid >> 4);
        const int ch = tid & 15;
        const bf16x8 vv = *(const bf16x8*)(smem + row * 136 + ch * 8);
        *(bf16x8*)(C + (size_t)(m0 + half * 64 + row) * N + n0 + ch * 8) = vv;
      }
    }
  } else {
    // QKV scatter. Tile is entirely within one part (N=2304 = 3x768, 6 tiles each).
    const int part = (n0 >= 1536) ? 2 : ((n0 >= 768) ? 1 : 0);
    const int w0 = n0 - part * 768;       // within-part col base
    const int h0 = w0 >> 6;               // first head in tile (tile = 2 heads)
    const int bb = m0 >> 12;
    for (int half = 0; half < 2; half++) {
      const int nb_ = ((m0 >> 6) & 63) + half;
      __syncthreads();
      if (wm == half) {
        if (part < 2) {
#pragma unroll
          for (int nt = 0; nt < 4; nt++)
#pragma unroll
            for (int mt = 0; mt < 4; mt++)
#pragma unroll
              for (int r = 0; r < 4; r++)
                smem[(mt * 16 + quad * 4 + r) * 136 + wn * 64 + nt * 16 + col] =
                    f2b(acc[mt][nt][r] + bsv[nt]);
        } else {
          // V: stage transposed [vslot=ncol][pos], pitch 72 (16B-aligned)
#pragma unroll
          for (int nt = 0; nt < 4; nt++) {
            const int ncol = wn * 64 + nt * 16 + col;
#pragma unroll
            for (int mt = 0; mt < 4; mt++) {
              bf16x4 pk;
#pragma unroll
              for (int r = 0; r < 4; r++) pk[r] = f2b(acc[mt][nt][r] + bsv[nt]);
              *(bf16x4*)(smem + ncol * 72 + mt * 16 + quad * 4) = pk;
            }
          }
        }
      }
      __syncthreads();
      const int j = tid >> 7;   // head within tile
      const size_t dbase = (size_t)((bb * 12 + h0 + j) * 64 + nb_) * 4096;
      if (part < 2) {
        bf16* dst = (part == 0) ? qout : kout;
#pragma unroll
        for (int rr = 0; rr < 4; rr++) {
          const int tsk = (tid & 127) + rr * 128;
          const int row = tsk >> 3, pc = tsk & 7;
          const bf16x8 vv = *(const bf16x8*)(smem + row * 136 + j * 64 + pc * 8);
          *(bf16x8*)(dst + dbase + row * 64 + pc * 8) = vv;
        }
      } else {
#pragma unroll
        for (int rr = 0; rr < 4; rr++) {
          const int tsk = (tid & 127) + rr * 128;
          const int dh = tsk >> 3, pc = tsk & 7;
          const bf16x8 vv = *(const bf16x8*)(smem + (j * 64 + dh) * 72 + pc * 8);
          *(bf16x8*)(vout + dbase + dh * 64 + pc * 8) = vv;
        }
      }
    }
  }
}

// ---------------- block-sparse attention, full batch ----------------
__global__ __launch_bounds__(256) void attn_kernel(
    const bf16* q, const bf16* __restrict__ kmat, const bf16* __restrict__ vT,
    const int* __restrict__ amask, const int* __restrict__ rand_idx, bf16* o) {
  __shared__ __align__(16) bf16 plds[4][16][32];
  const int idx = blockIdx.x;
  const int nb = idx & 63;
  const int bh = idx >> 6;           // bb*12+hh
  const int bb = bh / 12;
  const int tid = threadIdx.x;
  const int wv = tid >> 6, lane = tid & 63;
  const int col = lane & 15, quad = lane >> 4;

  int sel[8];
  sel[0] = 0; sel[1] = (nb + 63) & 63; sel[2] = nb; sel[3] = (nb + 1) & 63;
  sel[4] = 63;
  sel[5] = rand_idx[nb * 3 + 0];
  sel[6] = rand_idx[nb * 3 + 1];
  sel[7] = rand_idx[nb * 3 + 2];

  const size_t bhbase = (size_t)bh * 64;
  const bf16* qb = q + (bhbase + nb) * 4096;
  const int qrow = wv * 16 + col;
  const bf16x8 aq0 = *(const bf16x8*)(qb + qrow * 64 + quad * 8);
  const bf16x8 aq1 = *(const bf16x8*)(qb + qrow * 64 + 32 + quad * 8);

  float sreg[32][4];
#pragma unroll
  for (int sb = 0; sb < 8; sb++) {
    const bf16* kb = kmat + (bhbase + sel[sb]) * 4096;
    const int* mrow = amask + bb * 4096 + sel[sb] * 64;
#pragma unroll
    for (int c = 0; c < 4; c++) {
      const int kr = c * 16 + col;
      const bf16x8 bk0 = *(const bf16x8*)(kb + kr * 64 + quad * 8);
      const bf16x8 bk1 = *(const bf16x8*)(kb + kr * 64 + 32 + quad * 8);
      f32x4 t = {};
      t = mfma16(aq0, bk0, t);
      t = mfma16(aq1, bk1, t);
      const float bias = (mrow[kr] > 0) ? 0.0f : -1e9f;
      const int ti = sb * 4 + c;
#pragma unroll
      for (int r = 0; r < 4; r++) sreg[ti][r] = t[r] * 0.125f + bias;
    }
  }

  float mx[4] = {-1e30f, -1e30f, -1e30f, -1e30f};
#pragma unroll
  for (int ti = 0; ti < 32; ti++)
#pragma unroll
    for (int r = 0; r < 4; r++) mx[r] = fmaxf(mx[r], sreg[ti][r]);
#pragma unroll
  for (int off = 8; off >= 1; off >>= 1)
#pragma unroll
    for (int r = 0; r < 4; r++) mx[r] = fmaxf(mx[r], __shfl_xor(mx[r], off));

  float sm[4] = {0.f, 0.f, 0.f, 0.f};
#pragma unroll
  for (int ti = 0; ti < 32; ti++)
#pragma unroll
    for (int r = 0; r < 4; r++) {
      const float p = __expf(sreg[ti][r] - mx[r]);
      sreg[ti][r] = p; sm[r] += p;
    }
#pragma unroll
  for (int off = 8; off >= 1; off >>= 1)
#pragma unroll
    for (int r = 0; r < 4; r++) sm[r] += __shfl_xor(sm[r], off);
  float inv[4];
#pragma unroll
  for (int r = 0; r < 4; r++) inv[r] = 1.0f / sm[r];

  f32x4 oacc[4] = {};
#pragma unroll
  for (int kc = 0; kc < 16; kc++) {
    __syncthreads();
#pragma unroll
    for (int j = 0; j < 2; j++)
#pragma unroll
      for (int r = 0; r < 4; r++)
        plds[wv][quad * 4 + r][j * 16 + col] = f2b(sreg[kc * 2 + j][r] * inv[r]);
    __syncthreads();
    const bf16x8 ap = *(const bf16x8*)(&plds[wv][col][quad * 8]);
    const int sb = kc >> 1;
    const int koff = (kc & 1) * 32 + quad * 8;
    const bf16* vb = vT + (bhbase + sel[sb]) * 4096;
#pragma unroll
    for (int nt = 0; nt < 4; nt++) {
      const bf16x8 bvv = *(const bf16x8*)(vb + (nt * 16 + col) * 64 + koff);
      oacc[nt] = mfma16(ap, bvv, oacc[nt]);
    }
  }

  bf16* ob = o + (bhbase + nb) * 4096;
#pragma unroll
  for (int nt = 0; nt < 4; nt++)
#pragma unroll
    for (int r = 0; r < 4; r++)
      ob[(wv * 16 + quad * 4 + r) * 64 + nt * 16 + col] = f2b(oacc[nt][r]);
}

// ---------------- pooler ----------------
__global__ __launch_bounds__(768) void pooler_kernel(
    const bf16* __restrict__ h, const void* __restrict__ Wp,
    const void* __restrict__ bp, float* __restrict__ pooled,
    const int* __restrict__ dflag) {
  __shared__ float hrow[768];
  const int flag = dflag[0];
  const int bb = blockIdx.x;
  const int j = threadIdx.x;
  hrow[j] = b2f(h[(size_t)bb * 4096 * 768 + j]);
  __syncthreads();
  float acc = 0.0f;
#pragma unroll 8
  for (int d = 0; d < 768; d++) acc += hrow[d] * ldf(Wp, (size_t)d * 768 + j, flag);
  pooled[bb * 768 + j] = tanhf(acc + ldf(bp, j, flag));
}

// ---------------- classifier + double-softmax loss ----------------
__global__ __launch_bounds__(256) void cls_kernel(
    const float* __restrict__ pooled, const void* __restrict__ Wc, const void* __restrict__ bc,
    const int* __restrict__ label, void* __restrict__ out, const int* __restrict__ dflag) {
  __shared__ float lsum[8];
  const int flag = dflag[0];
  const int tid = threadIdx.x;
  const int p = tid >> 5, i = tid & 31;
  const int bb = p >> 1, c = p & 1;
  float acc = 0.0f;
  for (int d = i; d < 768; d += 32) acc += pooled[bb * 768 + d] * ldf(Wc, (size_t)d * 2 + c, flag);
#pragma unroll
  for (int off = 16; off >= 1; off >>= 1) acc += __shfl_xor(acc, off);
  if (i == 0) lsum[p] = acc;
  __syncthreads();
  if (tid == 0) {
    float res[9];
    float loss = 0.0f;
    for (int b = 0; b < 4; b++) {
      const float l0 = lsum[b * 2 + 0] + ldf(bc, 0, flag);
      const float l1 = lsum[b * 2 + 1] + ldf(bc, 1, flag);
      const float m = fmaxf(l0, l1);
      const float e0 = expf(l0 - m), e1 = expf(l1 - m);
      const float s = e0 + e1;
      const float p0 = e0 / s, p1 = e1 / s;
      res[b * 2] = p0; res[b * 2 + 1] = p1;
      const float mm = fmaxf(p0, p1);
      const float lse = mm + logf(expf(p0 - mm) + expf(p1 - mm));
      const float chosen = (label[b] == 0) ? p0 : p1;
      loss -= (chosen - lse);
    }
    res[8] = loss * 0.25f;
    if (flag) { bf16* o = (bf16*)out; for (int j = 0; j < 9; j++) o[j] = f2b(res[j]); }
    else      { float* o = (float*)out; for (int j = 0; j < 9; j++) o[j] = res[j]; }
  }
}

extern "C" void kernel_launch(void* const* d_in, const int* in_sizes, int n_in,
                              void* d_out, int out_size, void* d_ws, size_t ws_size,
                              hipStream_t stream) {
  const int* input_ids      = (const int*)d_in[0];
  const int* attention_mask = (const int*)d_in[1];
  const int* label          = (const int*)d_in[2];
  const int* rand_idx       = (const int*)d_in[3];
  const void* emb      = d_in[4];
  const void* pos_emb  = d_in[5];
  const void* ln_emb_g = d_in[6];
  const void* ln_emb_b = d_in[7];
  const void* Wqkv = d_in[8];
  const void* bqkv = d_in[9];
  const void* Wo   = d_in[10];
  const void* bo   = d_in[11];
  const void* ln1_g = d_in[12];
  const void* ln1_b = d_in[13];
  const void* Wff1 = d_in[14];
  const void* bff1 = d_in[15];
  const void* Wff2 = d_in[16];
  const void* bff2 = d_in[17];
  const void* ln2_g = d_in[18];
  const void* ln2_b = d_in[19];
  const void* Wp = d_in[20];
  const void* bp = d_in[21];
  const void* Wc = d_in[22];
  const void* bc = d_in[23];

  bf16* ws = (bf16*)d_ws;
  size_t off = 0;
  int* dflag = (int*)(ws + off); off += 8;
  bf16* WqkvT = ws + off; off += (size_t)2 * 2304 * 768;
  bf16* WoT   = ws + off; off += (size_t)2 * 768 * 768;
  bf16* Wff1T = ws + off; off += (size_t)2 * 3072 * 768;
  bf16* Wff2T = ws + off; off += (size_t)2 * 768 * 3072;
  bf16* hbuf  = ws + off; off += (size_t)16384 * 768;
  bf16* qo    = ws + off; off += (size_t)16384 * 768;   // Q then O (blocked)
  bf16* kbf   = ws + off; off += (size_t)16384 * 768;   // K (blocked)
  bf16* vbf   = ws + off; off += (size_t)16384 * 768;   // V^T (blocked)
  bf16* xbf   = ws + off; off += (size_t)16384 * 768;   // GEMM out (row-major)
  bf16* a1buf = ws + off; off += (size_t)16384 * 3072;  // gelu acts
  float* pooled = (float*)(ws + off); off += 6144;

  dim3 blk(256);

  probe_kernel<<<1, 64, 0, stream>>>((const uint32_t*)ln_emb_g, dflag);

  for (int l = 0; l < 2; l++) {
    transpose_k<<<dim3(72, 24), blk, 0, stream>>>(Wqkv, (size_t)l * 768 * 2304, WqkvT + (size_t)l * 2304 * 768, 768, 2304, dflag);
    transpose_k<<<dim3(24, 24), blk, 0, stream>>>(Wo, (size_t)l * 768 * 768, WoT + (size_t)l * 768 * 768, 768, 768, dflag);
    transpose_k<<<dim3(96, 24), blk, 0, stream>>>(Wff1, (size_t)l * 768 * 3072, Wff1T + (size_t)l * 3072 * 768, 768, 3072, dflag);
    transpose_k<<<dim3(24, 96), blk, 0, stream>>>(Wff2, (size_t)l * 3072 * 768, Wff2T + (size_t)l * 768 * 3072, 3072, 768, dflag);
  }

  embed_ln_kernel<<<16384, blk, 0, stream>>>(input_ids, emb, pos_emb, ln_emb_g, ln_emb_b, hbuf, dflag);

  for (int l = 0; l < 2; l++) {
    gemm_bt<2, false><<<dim3(128, 18), blk, 0, stream>>>(hbuf, WqkvT + (size_t)l * 2304 * 768, bqkv, (size_t)l * 2304,
                                                         nullptr, 2304, 768, qo, kbf, vbf, dflag);
    attn_kernel<<<3072, blk, 0, stream>>>(qo, kbf, vbf, attention_mask, rand_idx, qo);
    gemm_bt<0, true><<<dim3(128, 6), blk, 0, stream>>>(qo, WoT + (size_t)l * 768 * 768, bo, (size_t)l * 768,
                                                       xbf, 768, 768, nullptr, nullptr, nullptr, dflag);
    add_ln_kernel<<<16384, blk, 0, stream>>>(hbuf, xbf, ln1_g, ln1_b, (size_t)l * 768, dflag);
    gemm_bt<1, false><<<dim3(128, 24), blk, 0, stream>>>(hbuf, Wff1T + (size_t)l * 3072 * 768, bff1, (size_t)l * 3072,
                                                         a1buf, 3072, 768, nullptr, nullptr, nullptr, dflag);
    gemm_bt<0, false><<<dim3(128, 6), blk, 0, stream>>>(a1buf, Wff2T + (size_t)l * 768 * 3072, bff2, (size_t)l * 768,
                                                        xbf, 768, 3072, nullptr, nullptr, nullptr, dflag);
    add_ln_kernel<<<16384, blk, 0, stream>>>(hbuf, xbf, ln2_g, ln2_b, (size_t)l * 768, dflag);
  }

  pooler_kernel<<<4, dim3(768), 0, stream>>>(hbuf, Wp, bp, pooled, dflag);
  cls_kernel<<<1, blk, 0, stream>>>(pooled, Wc, bc, label, d_out, dflag);

  (void)in_sizes; (void)n_in; (void)out_size; (void)ws_size;
}